// Round 5
// baseline (153.592 us; speedup 1.0000x reference)
//
#include <hip/hip_runtime.h>
#include <hip/hip_bf16.h>

#define NSEQ 4096
#define FT 256
#define BK 64

typedef __attribute__((ext_vector_type(8))) short bf16x8;
typedef __attribute__((ext_vector_type(4))) float f32x4;
typedef __attribute__((ext_vector_type(2))) float f32x2;

__device__ __forceinline__ ushort f2bf(float f) {
  __hip_bfloat16 h = __float2bfloat16(f);
  return *reinterpret_cast<const ushort*>(&h);
}

// ---------------- Kernel A (unchanged): hT[b][o][n] = (seq @ W^T + b) bf16 ----------------
__device__ __forceinline__ int swz(int row, int byteInRow) {
  return row * 128 + (byteInRow ^ ((row & 7) << 4));
}

__device__ __forceinline__ void mma_step(const char* lAp, const char* lBp,
                                         int lane, int wm, int wn,
                                         f32x4 acc[2][4]) {
  const int r16 = lane & 15;
  const int g16 = (lane >> 4) * 16;
#pragma unroll
  for (int kk = 0; kk < 2; ++kk) {
    const int kb = kk * 64 + g16;
    bf16x8 a[2], b[4];
#pragma unroll
    for (int mi = 0; mi < 2; ++mi) {
      const int row = wm * 32 + mi * 16 + r16;
      a[mi] = *reinterpret_cast<const bf16x8*>(lAp + swz(row, kb));
    }
#pragma unroll
    for (int ni = 0; ni < 4; ++ni) {
      const int row = wn * 64 + ni * 16 + r16;
      b[ni] = *reinterpret_cast<const bf16x8*>(lBp + swz(row, kb));
    }
#pragma unroll
    for (int mi = 0; mi < 2; ++mi)
#pragma unroll
      for (int ni = 0; ni < 4; ++ni)
        acc[mi][ni] = __builtin_amdgcn_mfma_f32_16x16x32_bf16(a[mi], b[ni],
                                                             acc[mi][ni], 0, 0, 0);
  }
}

__global__ __launch_bounds__(512) void linear_kernel(
    const float* __restrict__ seq, const float* __restrict__ W,
    const float* __restrict__ bias, ushort* __restrict__ hT) {
  __shared__ __align__(16) ushort lA[2][64 * 64];
  __shared__ __align__(16) ushort lB[2][256 * 64];

  const int tid = threadIdx.x;
  const int lane = tid & 63;
  const int wid = tid >> 6;
  const int wm = wid >> 2, wn = wid & 3;
  const int m0 = blockIdx.x * 64;

  const int ar = tid >> 4, ac = tid & 15;

  f32x4 rA[2];
  f32x4 rB[8];

  auto gload = [&](int t) {
    const int k0 = t * BK;
#pragma unroll
    for (int p = 0; p < 2; ++p)
      rA[p] = *reinterpret_cast<const f32x4*>(
          seq + (size_t)(m0 + ar + p * 32) * FT + k0 + ac * 4);
#pragma unroll
    for (int p = 0; p < 8; ++p)
      rB[p] = *reinterpret_cast<const f32x4*>(
          W + (size_t)(ar + p * 32) * FT + k0 + ac * 4);
  };
  auto lwrite = [&](int buf) {
    char* lAp = (char*)lA[buf];
    char* lBp = (char*)lB[buf];
#pragma unroll
    for (int p = 0; p < 2; ++p) {
      ushort4 u = make_ushort4(f2bf(rA[p][0]), f2bf(rA[p][1]), f2bf(rA[p][2]), f2bf(rA[p][3]));
      *reinterpret_cast<ushort4*>(lAp + swz(ar + p * 32, ac * 8)) = u;
    }
#pragma unroll
    for (int p = 0; p < 8; ++p) {
      ushort4 u = make_ushort4(f2bf(rB[p][0]), f2bf(rB[p][1]), f2bf(rB[p][2]), f2bf(rB[p][3]));
      *reinterpret_cast<ushort4*>(lBp + swz(ar + p * 32, ac * 8)) = u;
    }
  };

  f32x4 acc[2][4];
  const f32x4 zero = {0.f, 0.f, 0.f, 0.f};
#pragma unroll
  for (int mi = 0; mi < 2; ++mi)
#pragma unroll
    for (int ni = 0; ni < 4; ++ni) acc[mi][ni] = zero;

  gload(0);
  lwrite(0);
  const int NTA = FT / BK;  // 4
  for (int t = 0; t < NTA; ++t) {
    const int cur = t & 1;
    __syncthreads();
    if (t + 1 < NTA) gload(t + 1);
    mma_step((const char*)lA[cur], (const char*)lB[cur], lane, wm, wn, acc);
    if (t + 1 < NTA) lwrite(cur ^ 1);
  }

#pragma unroll
  for (int mi = 0; mi < 2; ++mi) {
    const int grow = m0 + wm * 32 + mi * 16 + ((lane >> 4) << 2);
    const int batch = grow >> 12;
    const int n = grow & (NSEQ - 1);
#pragma unroll
    for (int ni = 0; ni < 4; ++ni) {
      const int o = wn * 64 + ni * 16 + (lane & 15);
      const float bo = bias[o];
      ushort4 u;
      u.x = f2bf(acc[mi][ni][0] + bo);
      u.y = f2bf(acc[mi][ni][1] + bo);
      u.z = f2bf(acc[mi][ni][2] + bo);
      u.w = f2bf(acc[mi][ni][3] + bo);
      *reinterpret_cast<ushort4*>(hT + (size_t)(batch * FT + o) * NSEQ + n) = u;
    }
  }
}

// ---------------- Kernel B: out = PReLU(adj @ h) ----------------
// BM=32, BN=256, BK=32. 512 thr (8 waves, each 32x32 out). Grid 512 = 2
// blocks/CU (two independent barrier domains). adj: 4 reg-sets, hT: 4 LDS
// buffers; both issued 3 tiles ahead; one counted vmcnt(6)/iter (3 vm/iter).
#define BKB 32
#define NTB (NSEQ / BKB)  // 128

// BK=32 swizzle: 16B granule index XOR (row & 3); 64B rows.
__global__ __launch_bounds__(512, 4) void bmm_prelu_kernel(
    const float* __restrict__ adj, const ushort* __restrict__ hT,
    const float* __restrict__ alphaP, float* __restrict__ out) {
  // [0,64K): 4 x 16KB hT bufs; [64K,68K): 2 x 2KB adj bufs
  __shared__ __align__(16) char smem[4 * 16384 + 2 * 2048];

  const int tid = threadIdx.x;
  const int lane = tid & 63;
  const int wid = tid >> 6;  // 0..7 = wave's column block

  // XCD-contiguous remap (bijective: 512 = 8 * 64).
  const int bid = blockIdx.x;
  const int sbid = (bid & 7) * 64 + (bid >> 3);
  const int batch = sbid >> 7;
  const int m0 = (sbid & 127) * 32;

  const float* adjB = adj + (size_t)batch * NSEQ * NSEQ + (size_t)m0 * NSEQ;
  const ushort* hTB = hT + (size_t)batch * FT * NSEQ;

  const int ar = tid >> 4, ac = tid & 15;        // adj: row 0..31, 2 floats
  const int brow = wid * 16 + (lane >> 2);       // hT row (+ p*128)
  const int bgsrc = (lane & 3) ^ ((lane >> 2) & 3);  // pre-swizzled granule

  f32x2 rA0, rA1, rA2, rA3;

  f32x4 acc[2][2];
  const f32x4 zero = {0.f, 0.f, 0.f, 0.f};
#pragma unroll
  for (int mi = 0; mi < 2; ++mi)
#pragma unroll
    for (int ni = 0; ni < 2; ++ni) acc[mi][ni] = zero;

  auto issueA = [&](int t, f32x2& r) {
    r = __builtin_nontemporal_load(reinterpret_cast<const f32x2*>(
        adjB + (size_t)ar * NSEQ + t * BKB + ac * 2));
  };
  auto issueB = [&](int t, int ib) {
    const int k0 = t * BKB;
#pragma unroll
    for (int p = 0; p < 2; ++p) {
      const ushort* gp = hTB + (size_t)(p * 128 + brow) * NSEQ + k0 + bgsrc * 8;
      char* lp = smem + ib * 16384 + p * 8192 + wid * 1024;
      __builtin_amdgcn_global_load_lds(
          (const __attribute__((address_space(1))) void*)gp,
          (__attribute__((address_space(3))) void*)lp, 16, 0, 0);
    }
  };
  auto writeA = [&](const f32x2& r, int ia) {
    char* lAp = smem + 65536 + ia * 2048;
    uint pack = (uint)f2bf(r[0]) | ((uint)f2bf(r[1]) << 16);
    *reinterpret_cast<uint*>(lAp + ar * 64 + ((ac * 4) ^ ((ar & 3) << 4))) = pack;
  };
  auto mma = [&](int ia, int ib) {
    const char* lAp = smem + 65536 + ia * 2048;
    const char* lBp = smem + ib * 16384;
    const int r16 = lane & 15;
    const int gofs = ((lane >> 4) ^ (lane & 3)) << 4;  // row&3 == lane&3 here
    bf16x8 a[2], b[2];
#pragma unroll
    for (int mi = 0; mi < 2; ++mi)
      a[mi] = *reinterpret_cast<const bf16x8*>(lAp + (mi * 16 + r16) * 64 + gofs);
#pragma unroll
    for (int ni = 0; ni < 2; ++ni)
      b[ni] = *reinterpret_cast<const bf16x8*>(
          lBp + (wid * 32 + ni * 16 + r16) * 64 + gofs);
#pragma unroll
    for (int mi = 0; mi < 2; ++mi)
#pragma unroll
      for (int ni = 0; ni < 2; ++ni)
        acc[mi][ni] = __builtin_amdgcn_mfma_f32_16x16x32_bf16(a[mi], b[ni],
                                                             acc[mi][ni], 0, 0, 0);
  };

  // Prologue: pinned issue order A0 B0 A1 B1 A2 B2 (1+2+1+2+1+2 = 9 vm ops).
  issueA(0, rA0); __builtin_amdgcn_sched_barrier(0);
  issueB(0, 0);   __builtin_amdgcn_sched_barrier(0);
  issueA(1, rA1); __builtin_amdgcn_sched_barrier(0);
  issueB(1, 1);   __builtin_amdgcn_sched_barrier(0);
  issueA(2, rA2); __builtin_amdgcn_sched_barrier(0);
  issueB(2, 2);   __builtin_amdgcn_sched_barrier(0);
  asm volatile("s_waitcnt vmcnt(8)" ::: "memory");  // A0 in regs
  writeA(rA0, 0);
  asm volatile("s_waitcnt vmcnt(6) lgkmcnt(0)" ::: "memory");  // B0 in LDS
  __builtin_amdgcn_s_barrier();
  __builtin_amdgcn_sched_barrier(0);

  // body(t): issue A(t+3),B(t+3); mma lA[t&1],lB[t&3]; vmcnt(6) drains
  // A(t+1)+B(t+1) (3 ops, leaves 6); writeA A(t+1); lgkm0; barrier.
  auto body = [&](int t, f32x2& rIss, const f32x2& rWr,
                  int ibIss, int ibRd, int iaRd, int iaWr) {
    issueA(t + 3, rIss);
    issueB(t + 3, ibIss);
    mma(iaRd, ibRd);
    asm volatile("s_waitcnt vmcnt(6)" ::: "memory");
    writeA(rWr, iaWr);
    asm volatile("s_waitcnt lgkmcnt(0)" ::: "memory");
    __builtin_amdgcn_s_barrier();
    __builtin_amdgcn_sched_barrier(0);
  };

  // t = 0..123 (static buffer/reg parity, period 4), then t = 124.
  for (int j = 0; j < 31; ++j) {
    const int t0 = j * 4;
    body(t0 + 0, rA3, rA1, 3, 0, 0, 1);
    body(t0 + 1, rA0, rA2, 0, 1, 1, 0);
    body(t0 + 2, rA1, rA3, 1, 2, 0, 1);
    body(t0 + 3, rA2, rA0, 2, 3, 1, 0);
  }
  body(124, rA3, rA1, 3, 0, 0, 1);
  {  // t = 125: no issue. Outstanding: A126,B126,A127,B127 = 6.
    mma(1, 1);
    asm volatile("s_waitcnt vmcnt(3)" ::: "memory");  // A126+B126 done
    writeA(rA2, 0);
    asm volatile("s_waitcnt lgkmcnt(0)" ::: "memory");
    __builtin_amdgcn_s_barrier();
    __builtin_amdgcn_sched_barrier(0);
  }
  {  // t = 126
    mma(0, 2);
    asm volatile("s_waitcnt vmcnt(0)" ::: "memory");  // A127+B127 done
    writeA(rA3, 1);
    asm volatile("s_waitcnt lgkmcnt(0)" ::: "memory");
    __builtin_amdgcn_s_barrier();
    __builtin_amdgcn_sched_barrier(0);
  }
  // t = 127
  mma(1, 3);

  // Epilogue: PReLU -> LDS transpose (32 x 264 f32 = 33.8 KB overlay) -> rows.
  const float alpha = *alphaP;
  __syncthreads();
  float* lo = (float*)smem;
  const int PITCH = 264;
#pragma unroll
  for (int mi = 0; mi < 2; ++mi) {
    const int rbase = mi * 16 + ((lane >> 4) << 2);
#pragma unroll
    for (int ni = 0; ni < 2; ++ni) {
      const int o = wid * 32 + ni * 16 + (lane & 15);
#pragma unroll
      for (int j = 0; j < 4; ++j) {
        float v = acc[mi][ni][j];
        v = v > 0.f ? v : alpha * v;
        lo[(rbase + j) * PITCH + o] = v;
      }
    }
  }
  __syncthreads();
  float* outB = out + ((size_t)batch * NSEQ + m0) * FT;
  const int r = tid >> 4, c16 = tid & 15;
#pragma unroll
  for (int k = 0; k < 4; ++k) {
    const int g = c16 + k * 16;
    f32x4 v = *reinterpret_cast<const f32x4*>(lo + r * PITCH + g * 4);
    __builtin_nontemporal_store(v, reinterpret_cast<f32x4*>(outB + (size_t)r * FT + g * 4));
  }
}

extern "C" void kernel_launch(void* const* d_in, const int* in_sizes, int n_in,
                              void* d_out, int out_size, void* d_ws, size_t ws_size,
                              hipStream_t stream) {
  const float* seq = (const float*)d_in[0];
  const float* adj = (const float*)d_in[1];
  const float* W = (const float*)d_in[2];
  const float* bias = (const float*)d_in[3];
  const float* alpha = (const float*)d_in[4];
  float* out = (float*)d_out;
  ushort* hT = (ushort*)d_ws;  // [4][256][4096] bf16 = 8 MB

  linear_kernel<<<256, 512, 0, stream>>>(seq, W, bias, hT);
  bmm_prelu_kernel<<<512, 512, 0, stream>>>(adj, hT, alpha, out);
}